// Round 1
// baseline (352.742 us; speedup 1.0000x reference)
//
#include <hip/hip_runtime.h>
#include <hip/hip_bf16.h>
#include <math.h>
#include <stdint.h>

typedef __bf16 bf16;
typedef __bf16 bf16x8 __attribute__((ext_vector_type(8)));
typedef __bf16 bf16x4 __attribute__((ext_vector_type(4)));
typedef float  f32x4  __attribute__((ext_vector_type(4)));

#define NTASKS 10
#define CAP    3
#define SEQ    128
#define HID    768
#define ADAPT  2048
#define BATCH  128
#define BL     (BATCH*SEQ)   /* 16384 */
#define NEGV   (-10000.0f)

__device__ __forceinline__ float sigmoidf_(float z) { return 1.f / (1.f + expf(-z)); }

// ---- async global->LDS, 16B per lane; LDS dest must be wave-uniform base ----
__device__ __forceinline__ void gld16(const void* g, void* l) {
    auto gp = (const __attribute__((address_space(1))) uint32_t*)g;
    auto lp = (__attribute__((address_space(3))) uint32_t*)(uint32_t)(uintptr_t)l;
    __builtin_amdgcn_global_load_lds(gp, lp, 16, 0, 0);
}

// ---------------- gates: sigmoid(s * e*) ----------------
__global__ void k_gates(const float* efc1, const float* efc2, const float* elarger,
                        const float* s, const int* tptr,
                        float* gfc1, float* gfc2, float* glarger) {
    int i = blockIdx.x * 256 + threadIdx.x;
    int t = *tptr; float sv = *s;
    if (i < ADAPT)                gfc1[i] = sigmoidf_(sv * efc1[t * ADAPT + i]);
    else if (i < ADAPT + HID)     { int j = i - ADAPT;        gfc2[j]    = sigmoidf_(sv * efc2[t * HID + j]); }
    else if (i < ADAPT + 2 * HID) { int j = i - ADAPT - HID;  glarger[j] = sigmoidf_(sv * elarger[t * HID + j]); }
}

// ---------------- fuse semantic fc1+fc2: W[j=n*3+c][h], bb[j] ----------------
__global__ void k_fusew(const float* sfc1_w, const float* sfc1_b,
                        const float* sfc2_w, const float* sfc2_b,
                        float* W, float* bb) {
    int j = blockIdx.x;        // 0..29
    int n = j / CAP;
    __shared__ float w2[100];
    if (threadIdx.x < 100) w2[threadIdx.x] = sfc2_w[j * 100 + threadIdx.x];
    __syncthreads();
    const float* w1 = sfc1_w + (size_t)n * 100 * HID;
    float a0 = 0, a1 = 0, a2 = 0;
    for (int k = 0; k < 100; ++k) {
        float s2 = w2[k];
        const float* r = w1 + k * HID;
        a0 += s2 * r[threadIdx.x];
        a1 += s2 * r[threadIdx.x + 256];
        a2 += s2 * r[threadIdx.x + 512];
    }
    W[j * HID + threadIdx.x]       = a0;
    W[j * HID + threadIdx.x + 256] = a1;
    W[j * HID + threadIdx.x + 512] = a2;
    if (threadIdx.x == 0) {
        float b = sfc2_b[j];
        for (int k = 0; k < 100; ++k) b += sfc1_b[n * 100 + k] * w2[k];
        bb[j] = b;
    }
}

// ---------------- fp32 -> bf16 weight conversion ----------------
__global__ void k_convert(const float* fc1_w, const float* fc2_w, bf16* B1, bf16* B2) {
    int i = blockIdx.x * 256 + threadIdx.x;
    const int quarter = ADAPT * HID / 4;  // 393216 float4's per weight
    if (i < quarter) {
        float4 v = ((const float4*)fc1_w)[i];
        bf16x4 o = { (bf16)v.x, (bf16)v.y, (bf16)v.z, (bf16)v.w };
        ((bf16x4*)B1)[i] = o;
    } else if (i < 2 * quarter) {
        int j = i - quarter;
        float4 v = ((const float4*)fc2_w)[j];
        bf16x4 o = { (bf16)v.x, (bf16)v.y, (bf16)v.z, (bf16)v.w };
        ((bf16x4*)B2)[j] = o;
    }
}

// ---------------- semantic caps + squash over tasks ----------------
// out: sem[b][n][l*3+c]   (f32)
__global__ void k_sem(const float* __restrict__ x, const float* __restrict__ W,
                      const float* __restrict__ bb, float* __restrict__ sem) {
    int bl = blockIdx.x;             // b*128 + l
    int tid = threadIdx.x;           // 256
    __shared__ float xs[HID];
    __shared__ float sr[32];
    __shared__ float scl[CAP];
    if (tid < 192) ((float4*)xs)[tid] = ((const float4*)(x + (size_t)bl * HID))[tid];
    __syncthreads();
    int g = tid >> 4, l16 = tid & 15;
    #pragma unroll
    for (int rep = 0; rep < 2; ++rep) {
        int j = g + rep * 16;
        if (j < 30) {
            const float* wr = W + j * HID;
            float a = 0.f;
            for (int i = l16; i < HID; i += 16) a += xs[i] * wr[i];
            a += __shfl_xor(a, 8); a += __shfl_xor(a, 4);
            a += __shfl_xor(a, 2); a += __shfl_xor(a, 1);
            if (l16 == 0) sr[j] = a + bb[j];
        }
    }
    __syncthreads();
    if (tid < CAP) {
        float sq = 0.f;
        #pragma unroll
        for (int n = 0; n < NTASKS; ++n) { float v = sr[n * CAP + tid]; sq += v * v; }
        scl[tid] = (sq / (1.f + sq)) / sqrtf(sq);
    }
    __syncthreads();
    if (tid < 30) {
        int n = tid / CAP, c = tid % CAP;
        int b = bl >> 7, l = bl & 127;
        sem[((size_t)b * NTASKS + n) * 384 + l * CAP + c] = sr[tid] * scl[c];
    }
}

// ---------------- priors[c][b][n][l] = sem[b][n][:] . rw[c][n][:][l] ----------------
__global__ void k_priors(const float* __restrict__ sem, const float* __restrict__ rw,
                         float* __restrict__ priors) {
    int cn = blockIdx.y;             // c*10+n
    int c = cn / NTASKS, n = cn % NTASKS;
    int b0 = blockIdx.x * 8;
    int l = threadIdx.x;             // 128
    __shared__ float sems[8][384];
    for (int bbi = 0; bbi < 8; ++bbi) {
        const float* srow = sem + ((size_t)(b0 + bbi) * NTASKS + n) * 384;
        for (int d = l; d < 384; d += 128) sems[bbi][d] = srow[d];
    }
    __syncthreads();
    float acc[8] = {};
    const float* rwp = rw + (size_t)cn * 384 * 128 + l;
    for (int d = 0; d < 384; ++d) {
        float rv = rwp[(size_t)d * 128];
        #pragma unroll
        for (int bbi = 0; bbi < 8; ++bbi) acc[bbi] += sems[bbi][d] * rv;
    }
    for (int bbi = 0; bbi < 8; ++bbi)
        priors[(((size_t)c * BATCH + b0 + bbi) * NTASKS + n) * 128 + l] = acc[bbi];
}

// ---------------- dynamic routing; logits are uniform over l ----------------
__global__ void k_routing(const float* __restrict__ priors, const int* tptr,
                          float* __restrict__ vote) {
    int cb = blockIdx.x;             // c*128+b
    int lane = threadIdx.x;          // 64
    int t = *tptr;
    float p0[NTASKS], p1[NTASKS], ln[NTASKS];
    const float* pb = priors + (size_t)cb * NTASKS * 128;
    #pragma unroll
    for (int n = 0; n < NTASKS; ++n) {
        p0[n] = pb[n * 128 + lane];
        p1[n] = pb[n * 128 + 64 + lane];
        ln[n] = 0.f;
    }
    float v0 = 0.f, v1 = 0.f;
    for (int it = 0; it < 3; ++it) {
        float lm[NTASKS];
        float mx = -3.4e38f;
        #pragma unroll
        for (int n = 0; n < NTASKS; ++n) { lm[n] = (n <= t) ? ln[n] : NEGV; mx = fmaxf(mx, lm[n]); }
        float e[NTASKS], se = 0.f;
        #pragma unroll
        for (int n = 0; n < NTASKS; ++n) { e[n] = expf(lm[n] - mx); se += e[n]; }
        float inv = 1.f / se;
        v0 = 0.f; v1 = 0.f;
        #pragma unroll
        for (int n = 0; n < NTASKS; ++n) { float pr = e[n] * inv; v0 += pr * p0[n]; v1 += pr * p1[n]; }
        if (it == 2) break;
        float sq = v0 * v0 + v1 * v1;
        #pragma unroll
        for (int m = 32; m >= 1; m >>= 1) sq += __shfl_xor(sq, m);
        float scale = (sq / (1.f + sq)) / sqrtf(sq);
        float o0 = v0 * scale, o1 = v1 * scale;
        #pragma unroll
        for (int n = 0; n < NTASKS; ++n) {
            float d = p0[n] * o0 + p1[n] * o1;
            #pragma unroll
            for (int m = 32; m >= 1; m >>= 1) d += __shfl_xor(d, m);
            ln[n] = lm[n] + d;
        }
    }
    vote[(size_t)cb * 128 + lane]      = v0;
    vote[(size_t)cb * 128 + 64 + lane] = v1;
}

// ---------------- h = x + (scrambled_vote @ larger_w^T + larger_b) * glarger  -> bf16 ----------------
__global__ void k_buildH(const float* __restrict__ x, const float* __restrict__ vote,
                         const float* __restrict__ lw, const float* __restrict__ lb,
                         const float* __restrict__ glarger, bf16* __restrict__ H) {
    int idx = blockIdx.x * 256 + threadIdx.x;   // over BL*192 float4 groups
    int bl = idx / 192, h4 = (idx % 192) * 4;
    float v0 = vote[bl * 3 + 0], v1 = vote[bl * 3 + 1], v2 = vote[bl * 3 + 2];
    float xa[4];
    *(float4*)xa = ((const float4*)x)[idx];
    bf16x4 o;
    #pragma unroll
    for (int r = 0; r < 4; ++r) {
        int hid = h4 + r;
        float hv = v0 * lw[hid * 3] + v1 * lw[hid * 3 + 1] + v2 * lw[hid * 3 + 2] + lb[hid];
        o[r] = (bf16)(xa[r] + hv * glarger[hid]);
    }
    ((bf16x4*)H)[idx] = o;
}

// ---------------- bf16 MFMA GEMM: C = act(A @ Bw^T + bias) * gate ----------------
// A: [M][K] bf16 row-major; Bw: [N][K] bf16 row-major (i.e. the torch weight).
// MODE 1: Out = bf16 H1[M][N].   MODE 2: Out = float, Out = X + val, N==HID.
template <int MODE>
__launch_bounds__(256)
__global__ void k_gemm(const bf16* __restrict__ A, const bf16* __restrict__ Bw,
                       const float* __restrict__ bias, const float* __restrict__ gate,
                       const float* __restrict__ X, void* __restrict__ Out,
                       int K, int N) {
    __shared__ __align__(16) bf16 As[128 * 32];
    __shared__ __align__(16) bf16 Bs[128 * 32];
    const int tid = threadIdx.x;
    const int wave = tid >> 6, lane = tid & 63;
    const int tm = blockIdx.x, tn = blockIdx.y;
    const int wr = wave >> 1, wc = wave & 1;

    f32x4 acc[4][4] = {};

    const bf16* Abase = A + (size_t)(tm * 128 + (tid >> 2)) * K + (tid & 3) * 8;
    const bf16* Bbase = Bw + (size_t)(tn * 128 + (tid >> 2)) * K + (tid & 3) * 8;
    bf16* AsW = As + wave * 512;   // wave-uniform LDS base (1024 B per wave)
    bf16* BsW = Bs + wave * 512;

    const int lr = lane & 15, kg = (lane >> 4) * 8;

    for (int k0 = 0; k0 < K; k0 += 32) {
        __syncthreads();   // previous compute done before overwrite
        gld16(Abase + k0, AsW);
        gld16(Abase + k0 + (size_t)64 * K, AsW + 2048);
        gld16(Bbase + k0, BsW);
        gld16(Bbase + k0 + (size_t)64 * K, BsW + 2048);
        __syncthreads();   // compiler drains vmcnt before barrier
        bf16x8 af[4], bfr[4];
        #pragma unroll
        for (int m = 0; m < 4; ++m)
            af[m] = *(const bf16x8*)&As[(wr * 64 + m * 16 + lr) * 32 + kg];
        #pragma unroll
        for (int n = 0; n < 4; ++n)
            bfr[n] = *(const bf16x8*)&Bs[(wc * 64 + n * 16 + lr) * 32 + kg];
        #pragma unroll
        for (int m = 0; m < 4; ++m)
            #pragma unroll
            for (int n = 0; n < 4; ++n)
                acc[m][n] = __builtin_amdgcn_mfma_f32_16x16x32_bf16(af[m], bfr[n], acc[m][n], 0, 0, 0);
    }

    #pragma unroll
    for (int n = 0; n < 4; ++n) {
        int col = tn * 128 + wc * 64 + n * 16 + lr;
        float bv = bias[col], gv = gate[col];
        #pragma unroll
        for (int m = 0; m < 4; ++m) {
            int row0 = tm * 128 + wr * 64 + m * 16 + (lane >> 4) * 4;
            #pragma unroll
            for (int r = 0; r < 4; ++r) {
                float v = acc[m][n][r] + bv;
                v = fmaxf(v, 0.f) * gv;
                int row = row0 + r;
                if (MODE == 1) {
                    ((bf16*)Out)[(size_t)row * N + col] = (bf16)v;
                } else {
                    size_t o = (size_t)row * HID + col;
                    ((float*)Out)[o] = X[o] + v;
                }
            }
        }
    }
}

extern "C" void kernel_launch(void* const* d_in, const int* in_sizes, int n_in,
                              void* d_out, int out_size, void* d_ws, size_t ws_size,
                              hipStream_t stream) {
    const float* x      = (const float*)d_in[0];
    const int*   t      = (const int*)  d_in[1];
    const float* s      = (const float*)d_in[2];
    const float* fc1_w  = (const float*)d_in[3];
    const float* fc1_b  = (const float*)d_in[4];
    const float* fc2_w  = (const float*)d_in[5];
    const float* fc2_b  = (const float*)d_in[6];
    const float* efc1   = (const float*)d_in[7];
    const float* efc2   = (const float*)d_in[8];
    const float* sfc1_w = (const float*)d_in[9];
    const float* sfc1_b = (const float*)d_in[10];
    const float* sfc2_w = (const float*)d_in[11];
    const float* sfc2_b = (const float*)d_in[12];
    const float* rw     = (const float*)d_in[13];
    const float* lw     = (const float*)d_in[14];
    const float* lb     = (const float*)d_in[15];
    const float* elarger= (const float*)d_in[16];

    char* ws = (char*)d_ws;
    size_t off = 0;
    auto alloc = [&](size_t b) { void* p = ws + off; off = (off + b + 255) & ~(size_t)255; return p; };
    float* gfc1    = (float*)alloc(ADAPT * 4);
    float* gfc2    = (float*)alloc(HID * 4);
    float* glarger = (float*)alloc(HID * 4);
    float* W       = (float*)alloc(30 * HID * 4);
    float* bb      = (float*)alloc(32 * 4);
    bf16*  B1      = (bf16*) alloc((size_t)ADAPT * HID * 2);
    bf16*  B2      = (bf16*) alloc((size_t)ADAPT * HID * 2);
    float* sem     = (float*)alloc((size_t)BATCH * NTASKS * 384 * 4);
    float* priors  = (float*)alloc((size_t)CAP * BATCH * NTASKS * 128 * 4);
    float* vote    = (float*)alloc((size_t)CAP * BATCH * 128 * 4);
    bf16*  H1      = (bf16*) alloc((size_t)BL * ADAPT * 2);
    bf16*  H       = (bf16*)d_out;  // stage bf16 h in the (larger) output buffer

    k_gates  <<<14, 256, 0, stream>>>(efc1, efc2, elarger, s, t, gfc1, gfc2, glarger);
    k_fusew  <<<30, 256, 0, stream>>>(sfc1_w, sfc1_b, sfc2_w, sfc2_b, W, bb);
    k_convert<<<3072, 256, 0, stream>>>(fc1_w, fc2_w, B1, B2);
    k_sem    <<<BL, 256, 0, stream>>>(x, W, bb, sem);
    k_priors <<<dim3(16, 30), 128, 0, stream>>>(sem, rw, priors);
    k_routing<<<CAP * BATCH, 64, 0, stream>>>(priors, t, vote);
    k_buildH <<<BL * 192 / 256, 256, 0, stream>>>(x, vote, lw, lb, glarger, H);
    k_gemm<1><<<dim3(128, 16), 256, 0, stream>>>(H,  B1, fc1_b, gfc1, nullptr, H1,   HID,   ADAPT);
    k_gemm<2><<<dim3(128, 6),  256, 0, stream>>>(H1, B2, fc2_b, gfc2, x,       d_out, ADAPT, HID);
}

// Round 2
// 308.437 us; speedup vs baseline: 1.1436x; 1.1436x over previous
//
#include <hip/hip_runtime.h>
#include <hip/hip_bf16.h>
#include <math.h>
#include <stdint.h>

typedef __bf16 bf16;
typedef __bf16 bf16x8 __attribute__((ext_vector_type(8)));
typedef __bf16 bf16x4 __attribute__((ext_vector_type(4)));
typedef float  f32x4  __attribute__((ext_vector_type(4)));

#define NTASKS 10
#define CAP    3
#define SEQ    128
#define HID    768
#define ADAPT  2048
#define BATCH  128
#define BL     (BATCH*SEQ)   /* 16384 */
#define NEGV   (-10000.0f)

__device__ __forceinline__ float sigmoidf_(float z) { return 1.f / (1.f + expf(-z)); }

// ---- async global->LDS, 16B per lane; LDS dest must be wave-uniform base ----
__device__ __forceinline__ void gld16(const void* g, void* l) {
    auto gp = (const __attribute__((address_space(1))) uint32_t*)g;
    auto lp = (__attribute__((address_space(3))) uint32_t*)(uint32_t)(uintptr_t)l;
    __builtin_amdgcn_global_load_lds(gp, lp, 16, 0, 0);
}

// ---------------- gates: sigmoid(s * e*) ----------------
__global__ void k_gates(const float* efc1, const float* efc2, const float* elarger,
                        const float* s, const int* tptr,
                        float* gfc1, float* gfc2, float* glarger) {
    int i = blockIdx.x * 256 + threadIdx.x;
    int t = *tptr; float sv = *s;
    if (i < ADAPT)                gfc1[i] = sigmoidf_(sv * efc1[t * ADAPT + i]);
    else if (i < ADAPT + HID)     { int j = i - ADAPT;        gfc2[j]    = sigmoidf_(sv * efc2[t * HID + j]); }
    else if (i < ADAPT + 2 * HID) { int j = i - ADAPT - HID;  glarger[j] = sigmoidf_(sv * elarger[t * HID + j]); }
}

// ---- fuse semantic fc1+fc2 into bf16 Wb[32][768] (rows 30,31 zero) + f32 bb[32] ----
__global__ void k_fusew(const float* sfc1_w, const float* sfc1_b,
                        const float* sfc2_w, const float* sfc2_b,
                        bf16* Wb, float* bb) {
    int j = blockIdx.x;        // 0..31
    int n = j / CAP;
    if (j >= 30) {
        for (int i = threadIdx.x; i < HID; i += 256) Wb[j * HID + i] = (bf16)0.f;
        if (threadIdx.x == 0) bb[j] = 0.f;
        return;
    }
    __shared__ float w2[100];
    if (threadIdx.x < 100) w2[threadIdx.x] = sfc2_w[j * 100 + threadIdx.x];
    __syncthreads();
    const float* w1 = sfc1_w + (size_t)n * 100 * HID;
    float a0 = 0, a1 = 0, a2 = 0;
    for (int k = 0; k < 100; ++k) {
        float s2 = w2[k];
        const float* r = w1 + k * HID;
        a0 += s2 * r[threadIdx.x];
        a1 += s2 * r[threadIdx.x + 256];
        a2 += s2 * r[threadIdx.x + 512];
    }
    Wb[j * HID + threadIdx.x]       = (bf16)a0;
    Wb[j * HID + threadIdx.x + 256] = (bf16)a1;
    Wb[j * HID + threadIdx.x + 512] = (bf16)a2;
    if (threadIdx.x == 0) {
        float b = sfc2_b[j];
        for (int k = 0; k < 100; ++k) b += sfc1_b[n * 100 + k] * w2[k];
        bb[j] = b;
    }
}

// ---------------- fp32 -> bf16 weight conversion ----------------
__global__ void k_convert(const float* fc1_w, const float* fc2_w, bf16* B1, bf16* B2) {
    int i = blockIdx.x * 256 + threadIdx.x;
    const int quarter = ADAPT * HID / 4;  // 393216 float4's per weight
    if (i < quarter) {
        float4 v = ((const float4*)fc1_w)[i];
        bf16x4 o = { (bf16)v.x, (bf16)v.y, (bf16)v.z, (bf16)v.w };
        ((bf16x4*)B1)[i] = o;
    } else if (i < 2 * quarter) {
        int j = i - quarter;
        float4 v = ((const float4*)fc2_w)[j];
        bf16x4 o = { (bf16)v.x, (bf16)v.y, (bf16)v.z, (bf16)v.w };
        ((bf16x4*)B2)[j] = o;
    }
}

// ---------------- semantic caps via MFMA + fused squash ----------------
// 64-row M tile, N=32 (30 used). x converted f32->bf16 in-register.
// out: sem[b][n][l*3+c]
__launch_bounds__(256)
__global__ void k_semg(const float* __restrict__ x, const bf16* __restrict__ Wb,
                       const float* __restrict__ bb, float* __restrict__ sem) {
    __shared__ __align__(16) bf16 As[64 * 32];
    __shared__ __align__(16) bf16 Bs[32 * 32];
    __shared__ float sem_s[64][33];
    const int tid = threadIdx.x;
    const int wave = tid >> 6, lane = tid & 63;
    const int tm = blockIdx.x;
    const int lr = lane & 15, kg = (lane >> 4) * 8;
    f32x4 acc[2] = {};

    const float* xbase = x + (size_t)(tm * 64 + (tid >> 2)) * HID + (tid & 3) * 8;
    const bf16* wbase = Wb + (size_t)(tid >> 2) * HID + (tid & 3) * 8;  // valid for tid<128
    bf16* BsW = Bs + wave * 512;

    for (int k0 = 0; k0 < HID; k0 += 32) {
        float xv[8];
        *(float4*)&xv[0] = *(const float4*)(xbase + k0);
        *(float4*)&xv[4] = *(const float4*)(xbase + k0 + 4);
        __syncthreads();                       // prior compute done before overwrite
        if (tid < 128) gld16(wbase + k0, BsW); // waves 0,1 stage W tile (2 KB)
        bf16x8 xb;
        #pragma unroll
        for (int i = 0; i < 8; ++i) xb[i] = (bf16)xv[i];
        *(bf16x8*)&As[tid * 8] = xb;           // row tid>>2, col (tid&3)*8
        __syncthreads();
        bf16x8 af = *(const bf16x8*)&As[(wave * 16 + lr) * 32 + kg];
        bf16x8 b0 = *(const bf16x8*)&Bs[lr * 32 + kg];
        bf16x8 b1 = *(const bf16x8*)&Bs[(16 + lr) * 32 + kg];
        acc[0] = __builtin_amdgcn_mfma_f32_16x16x32_bf16(af, b0, acc[0], 0, 0, 0);
        acc[1] = __builtin_amdgcn_mfma_f32_16x16x32_bf16(af, b1, acc[1], 0, 0, 0);
    }

    #pragma unroll
    for (int n = 0; n < 2; ++n) {
        int col = n * 16 + lr;
        float bv = bb[col];
        #pragma unroll
        for (int r = 0; r < 4; ++r) {
            int row = wave * 16 + (lane >> 4) * 4 + r;
            sem_s[row][col] = acc[n][r] + bv;
        }
    }
    __syncthreads();
    if (tid < 64) {
        int bl = tm * 64 + tid;
        int b = bl >> 7, l = bl & 127;
        float vals[30];
        float sq[3] = {0.f, 0.f, 0.f};
        #pragma unroll
        for (int j = 0; j < 30; ++j) { float v = sem_s[tid][j]; vals[j] = v; sq[j % 3] += v * v; }
        float scl[3];
        #pragma unroll
        for (int c = 0; c < 3; ++c) scl[c] = (sq[c] / (1.f + sq[c])) / sqrtf(sq[c]);
        float* op = sem + (size_t)b * NTASKS * 384 + l * 3;
        #pragma unroll
        for (int j = 0; j < 30; ++j) op[(j / 3) * 384 + (j % 3)] = vals[j] * scl[j % 3];
    }
}

// ---------------- priors[c][b][n][l] = sem[b][n][:] . rw[c][n][:][l] ----------------
#define BBI 16
__global__ void k_priors(const float* __restrict__ sem, const float* __restrict__ rw,
                         float* __restrict__ priors) {
    int cn = blockIdx.y;             // c*10+n
    int c = cn / NTASKS, n = cn % NTASKS;
    int b0 = blockIdx.x * BBI;
    int l = threadIdx.x;             // 128
    __shared__ float sems[BBI][384];
    for (int bbi = 0; bbi < BBI; ++bbi) {
        const float* srow = sem + ((size_t)(b0 + bbi) * NTASKS + n) * 384;
        for (int d = l; d < 384; d += 128) sems[bbi][d] = srow[d];
    }
    __syncthreads();
    float acc[BBI] = {};
    const float* rwp = rw + (size_t)cn * 384 * 128 + l;
    for (int d = 0; d < 384; ++d) {
        float rv = rwp[(size_t)d * 128];
        #pragma unroll
        for (int bbi = 0; bbi < BBI; ++bbi) acc[bbi] += sems[bbi][d] * rv;
    }
    for (int bbi = 0; bbi < BBI; ++bbi)
        priors[(((size_t)c * BATCH + b0 + bbi) * NTASKS + n) * 128 + l] = acc[bbi];
}

// ---------------- dynamic routing; logits are uniform over l ----------------
__global__ void k_routing(const float* __restrict__ priors, const int* tptr,
                          float* __restrict__ vote) {
    int cb = blockIdx.x;             // c*128+b
    int lane = threadIdx.x;          // 64
    int t = *tptr;
    float p0[NTASKS], p1[NTASKS], ln[NTASKS];
    const float* pb = priors + (size_t)cb * NTASKS * 128;
    #pragma unroll
    for (int n = 0; n < NTASKS; ++n) {
        p0[n] = pb[n * 128 + lane];
        p1[n] = pb[n * 128 + 64 + lane];
        ln[n] = 0.f;
    }
    float v0 = 0.f, v1 = 0.f;
    for (int it = 0; it < 3; ++it) {
        float lm[NTASKS];
        float mx = -3.4e38f;
        #pragma unroll
        for (int n = 0; n < NTASKS; ++n) { lm[n] = (n <= t) ? ln[n] : NEGV; mx = fmaxf(mx, lm[n]); }
        float e[NTASKS], se = 0.f;
        #pragma unroll
        for (int n = 0; n < NTASKS; ++n) { e[n] = expf(lm[n] - mx); se += e[n]; }
        float inv = 1.f / se;
        v0 = 0.f; v1 = 0.f;
        #pragma unroll
        for (int n = 0; n < NTASKS; ++n) { float pr = e[n] * inv; v0 += pr * p0[n]; v1 += pr * p1[n]; }
        if (it == 2) break;
        float sq = v0 * v0 + v1 * v1;
        #pragma unroll
        for (int m = 32; m >= 1; m >>= 1) sq += __shfl_xor(sq, m);
        float scale = (sq / (1.f + sq)) / sqrtf(sq);
        float o0 = v0 * scale, o1 = v1 * scale;
        #pragma unroll
        for (int n = 0; n < NTASKS; ++n) {
            float d = p0[n] * o0 + p1[n] * o1;
            #pragma unroll
            for (int m = 32; m >= 1; m >>= 1) d += __shfl_xor(d, m);
            ln[n] = lm[n] + d;
        }
    }
    vote[(size_t)cb * 128 + lane]      = v0;
    vote[(size_t)cb * 128 + 64 + lane] = v1;
}

// ---------------- h = x + (scrambled_vote @ larger_w^T + larger_b) * glarger  -> bf16 ----------------
__global__ void k_buildH(const float* __restrict__ x, const float* __restrict__ vote,
                         const float* __restrict__ lw, const float* __restrict__ lb,
                         const float* __restrict__ glarger, bf16* __restrict__ H) {
    int idx = blockIdx.x * 256 + threadIdx.x;   // over BL*192 float4 groups
    int bl = idx / 192, h4 = (idx % 192) * 4;
    float v0 = vote[bl * 3 + 0], v1 = vote[bl * 3 + 1], v2 = vote[bl * 3 + 2];
    float xa[4];
    *(float4*)xa = ((const float4*)x)[idx];
    bf16x4 o;
    #pragma unroll
    for (int r = 0; r < 4; ++r) {
        int hid = h4 + r;
        float hv = v0 * lw[hid * 3] + v1 * lw[hid * 3 + 1] + v2 * lw[hid * 3 + 2] + lb[hid];
        o[r] = (bf16)(xa[r] + hv * glarger[hid]);
    }
    ((bf16x4*)H)[idx] = o;
}

// ---------------- bf16 MFMA GEMM: C = act(A @ Bw^T + bias) * gate ----------------
// A: [M][K] bf16 row-major; Bw: [N][K] bf16 row-major (torch weight layout).
// MODE 1: Out = bf16 H1[M][N].   MODE 2: Out = float, Out = X + val, N==HID.
template <int MODE>
__launch_bounds__(256)
__global__ void k_gemm(const bf16* __restrict__ A, const bf16* __restrict__ Bw,
                       const float* __restrict__ bias, const float* __restrict__ gate,
                       const float* __restrict__ X, void* __restrict__ Out,
                       int K, int N) {
    __shared__ __align__(16) bf16 As[128 * 32];
    __shared__ __align__(16) bf16 Bs[128 * 32];
    const int tid = threadIdx.x;
    const int wave = tid >> 6, lane = tid & 63;
    const int tm = blockIdx.x, tn = blockIdx.y;
    const int wr = wave >> 1, wc = wave & 1;

    f32x4 acc[4][4] = {};

    const bf16* Abase = A + (size_t)(tm * 128 + (tid >> 2)) * K + (tid & 3) * 8;
    const bf16* Bbase = Bw + (size_t)(tn * 128 + (tid >> 2)) * K + (tid & 3) * 8;
    bf16* AsW = As + wave * 512;   // wave-uniform LDS base (1024 B per wave)
    bf16* BsW = Bs + wave * 512;

    const int lr = lane & 15, kg = (lane >> 4) * 8;

    for (int k0 = 0; k0 < K; k0 += 32) {
        __syncthreads();   // previous compute done before overwrite
        gld16(Abase + k0, AsW);
        gld16(Abase + k0 + (size_t)64 * K, AsW + 2048);
        gld16(Bbase + k0, BsW);
        gld16(Bbase + k0 + (size_t)64 * K, BsW + 2048);
        __syncthreads();   // compiler drains vmcnt before barrier
        bf16x8 af[4], bfr[4];
        #pragma unroll
        for (int m = 0; m < 4; ++m)
            af[m] = *(const bf16x8*)&As[(wr * 64 + m * 16 + lr) * 32 + kg];
        #pragma unroll
        for (int n = 0; n < 4; ++n)
            bfr[n] = *(const bf16x8*)&Bs[(wc * 64 + n * 16 + lr) * 32 + kg];
        #pragma unroll
        for (int m = 0; m < 4; ++m)
            #pragma unroll
            for (int n = 0; n < 4; ++n)
                acc[m][n] = __builtin_amdgcn_mfma_f32_16x16x32_bf16(af[m], bfr[n], acc[m][n], 0, 0, 0);
    }

    #pragma unroll
    for (int n = 0; n < 4; ++n) {
        int col = tn * 128 + wc * 64 + n * 16 + lr;
        float bv = bias[col], gv = gate[col];
        #pragma unroll
        for (int m = 0; m < 4; ++m) {
            int row0 = tm * 128 + wr * 64 + m * 16 + (lane >> 4) * 4;
            #pragma unroll
            for (int r = 0; r < 4; ++r) {
                float v = acc[m][n][r] + bv;
                v = fmaxf(v, 0.f) * gv;
                int row = row0 + r;
                if (MODE == 1) {
                    ((bf16*)Out)[(size_t)row * N + col] = (bf16)v;
                } else {
                    size_t o = (size_t)row * HID + col;
                    ((float*)Out)[o] = X[o] + v;
                }
            }
        }
    }
}

extern "C" void kernel_launch(void* const* d_in, const int* in_sizes, int n_in,
                              void* d_out, int out_size, void* d_ws, size_t ws_size,
                              hipStream_t stream) {
    const float* x      = (const float*)d_in[0];
    const int*   t      = (const int*)  d_in[1];
    const float* s      = (const float*)d_in[2];
    const float* fc1_w  = (const float*)d_in[3];
    const float* fc1_b  = (const float*)d_in[4];
    const float* fc2_w  = (const float*)d_in[5];
    const float* fc2_b  = (const float*)d_in[6];
    const float* efc1   = (const float*)d_in[7];
    const float* efc2   = (const float*)d_in[8];
    const float* sfc1_w = (const float*)d_in[9];
    const float* sfc1_b = (const float*)d_in[10];
    const float* sfc2_w = (const float*)d_in[11];
    const float* sfc2_b = (const float*)d_in[12];
    const float* rw     = (const float*)d_in[13];
    const float* lw     = (const float*)d_in[14];
    const float* lb     = (const float*)d_in[15];
    const float* elarger= (const float*)d_in[16];

    char* ws = (char*)d_ws;
    size_t off = 0;
    auto alloc = [&](size_t b) { void* p = ws + off; off = (off + b + 255) & ~(size_t)255; return p; };
    float* gfc1    = (float*)alloc(ADAPT * 4);
    float* gfc2    = (float*)alloc(HID * 4);
    float* glarger = (float*)alloc(HID * 4);
    bf16*  Wb      = (bf16*) alloc(32 * HID * 2);
    float* bb      = (float*)alloc(32 * 4);
    bf16*  B1      = (bf16*) alloc((size_t)ADAPT * HID * 2);
    bf16*  B2      = (bf16*) alloc((size_t)ADAPT * HID * 2);
    float* sem     = (float*)alloc((size_t)BATCH * NTASKS * 384 * 4);
    float* priors  = (float*)alloc((size_t)CAP * BATCH * NTASKS * 128 * 4);
    float* vote    = (float*)alloc((size_t)CAP * BATCH * 128 * 4);
    bf16*  H1      = (bf16*) alloc((size_t)BL * ADAPT * 2);
    bf16*  H       = (bf16*)d_out;  // stage bf16 h in the (larger) output buffer

    k_gates  <<<14, 256, 0, stream>>>(efc1, efc2, elarger, s, t, gfc1, gfc2, glarger);
    k_fusew  <<<32, 256, 0, stream>>>(sfc1_w, sfc1_b, sfc2_w, sfc2_b, Wb, bb);
    k_convert<<<3072, 256, 0, stream>>>(fc1_w, fc2_w, B1, B2);
    k_semg   <<<BL / 64, 256, 0, stream>>>(x, Wb, bb, sem);
    k_priors <<<dim3(BATCH / BBI, 30), 128, 0, stream>>>(sem, rw, priors);
    k_routing<<<CAP * BATCH, 64, 0, stream>>>(priors, t, vote);
    k_buildH <<<BL * 192 / 256, 256, 0, stream>>>(x, vote, lw, lb, glarger, H);
    k_gemm<1><<<dim3(128, 16), 256, 0, stream>>>(H,  B1, fc1_b, gfc1, nullptr, H1,   HID,   ADAPT);
    k_gemm<2><<<dim3(128, 6),  256, 0, stream>>>(H1, B2, fc2_b, gfc2, x,       d_out, ADAPT, HID);
}

// Round 3
// 259.051 us; speedup vs baseline: 1.3617x; 1.1906x over previous
//
#include <hip/hip_runtime.h>
#include <hip/hip_bf16.h>
#include <math.h>
#include <stdint.h>

typedef __bf16 bf16;
typedef __bf16 bf16x8 __attribute__((ext_vector_type(8)));
typedef __bf16 bf16x4 __attribute__((ext_vector_type(4)));
typedef float  f32x4  __attribute__((ext_vector_type(4)));

#define NTASKS 10
#define CAP    3
#define SEQ    128
#define HID    768
#define ADAPT  2048
#define BATCH  128
#define BL     (BATCH*SEQ)   /* 16384 */
#define NEGV   (-10000.0f)

__device__ __forceinline__ float sigmoidf_(float z) { return 1.f / (1.f + expf(-z)); }

// ---- async global->LDS, 16B per lane; LDS dest = wave-uniform base + lane*16 ----
__device__ __forceinline__ void gld16(const void* g, void* l) {
    auto gp = (const __attribute__((address_space(1))) uint32_t*)g;
    auto lp = (__attribute__((address_space(3))) uint32_t*)(uint32_t)(uintptr_t)l;
    __builtin_amdgcn_global_load_lds(gp, lp, 16, 0, 0);
}

// ---------------- gates: sigmoid(s * e*) ----------------
__global__ void k_gates(const float* efc1, const float* efc2, const float* elarger,
                        const float* s, const int* tptr,
                        float* gfc1, float* gfc2, float* glarger) {
    int i = blockIdx.x * 256 + threadIdx.x;
    int t = *tptr; float sv = *s;
    if (i < ADAPT)                gfc1[i] = sigmoidf_(sv * efc1[t * ADAPT + i]);
    else if (i < ADAPT + HID)     { int j = i - ADAPT;        gfc2[j]    = sigmoidf_(sv * efc2[t * HID + j]); }
    else if (i < ADAPT + 2 * HID) { int j = i - ADAPT - HID;  glarger[j] = sigmoidf_(sv * elarger[t * HID + j]); }
}

// ---- fuse semantic fc1+fc2 into bf16 Wb[32][768] (rows 30,31 zero) + f32 bb[32] ----
__global__ void k_fusew(const float* sfc1_w, const float* sfc1_b,
                        const float* sfc2_w, const float* sfc2_b,
                        bf16* Wb, float* bb) {
    int j = blockIdx.x;        // 0..31
    int n = j / CAP;
    if (j >= 30) {
        for (int i = threadIdx.x; i < HID; i += 256) Wb[j * HID + i] = (bf16)0.f;
        if (threadIdx.x == 0) bb[j] = 0.f;
        return;
    }
    __shared__ float w2[100];
    if (threadIdx.x < 100) w2[threadIdx.x] = sfc2_w[j * 100 + threadIdx.x];
    __syncthreads();
    const float* w1 = sfc1_w + (size_t)n * 100 * HID;
    float a0 = 0, a1 = 0, a2 = 0;
    for (int k = 0; k < 100; ++k) {
        float s2 = w2[k];
        const float* r = w1 + k * HID;
        a0 += s2 * r[threadIdx.x];
        a1 += s2 * r[threadIdx.x + 256];
        a2 += s2 * r[threadIdx.x + 512];
    }
    Wb[j * HID + threadIdx.x]       = (bf16)a0;
    Wb[j * HID + threadIdx.x + 256] = (bf16)a1;
    Wb[j * HID + threadIdx.x + 512] = (bf16)a2;
    if (threadIdx.x == 0) {
        float b = sfc2_b[j];
        for (int k = 0; k < 100; ++k) b += sfc1_b[n * 100 + k] * w2[k];
        bb[j] = b;
    }
}

// ---------------- fp32 -> bf16 weight conversion ----------------
__global__ void k_convert(const float* fc1_w, const float* fc2_w, bf16* B1, bf16* B2) {
    int i = blockIdx.x * 256 + threadIdx.x;
    const int quarter = ADAPT * HID / 4;  // 393216 float4's per weight
    if (i < quarter) {
        float4 v = ((const float4*)fc1_w)[i];
        bf16x4 o = { (bf16)v.x, (bf16)v.y, (bf16)v.z, (bf16)v.w };
        ((bf16x4*)B1)[i] = o;
    } else if (i < 2 * quarter) {
        int j = i - quarter;
        float4 v = ((const float4*)fc2_w)[j];
        bf16x4 o = { (bf16)v.x, (bf16)v.y, (bf16)v.z, (bf16)v.w };
        ((bf16x4*)B2)[j] = o;
    }
}

// ---------------- semantic caps via MFMA + fused squash ----------------
__launch_bounds__(256)
__global__ void k_semg(const float* __restrict__ x, const bf16* __restrict__ Wb,
                       const float* __restrict__ bb, float* __restrict__ sem) {
    __shared__ __align__(16) bf16 As[64 * 32];
    __shared__ __align__(16) bf16 Bs[32 * 32];
    __shared__ float sem_s[64][33];
    const int tid = threadIdx.x;
    const int wave = tid >> 6, lane = tid & 63;
    const int tm = blockIdx.x;
    const int lr = lane & 15, kg = (lane >> 4) * 8;
    f32x4 acc[2] = {};

    const float* xbase = x + (size_t)(tm * 64 + (tid >> 2)) * HID + (tid & 3) * 8;
    const bf16* wbase = Wb + (size_t)(tid >> 2) * HID + (tid & 3) * 8;  // valid for tid<128
    bf16* BsW = Bs + wave * 512;

    for (int k0 = 0; k0 < HID; k0 += 32) {
        float xv[8];
        *(float4*)&xv[0] = *(const float4*)(xbase + k0);
        *(float4*)&xv[4] = *(const float4*)(xbase + k0 + 4);
        __syncthreads();
        if (tid < 128) gld16(wbase + k0, BsW);
        bf16x8 xb;
        #pragma unroll
        for (int i = 0; i < 8; ++i) xb[i] = (bf16)xv[i];
        *(bf16x8*)&As[tid * 8] = xb;
        __syncthreads();
        bf16x8 af = *(const bf16x8*)&As[(wave * 16 + lr) * 32 + kg];
        bf16x8 b0 = *(const bf16x8*)&Bs[lr * 32 + kg];
        bf16x8 b1 = *(const bf16x8*)&Bs[(16 + lr) * 32 + kg];
        acc[0] = __builtin_amdgcn_mfma_f32_16x16x32_bf16(af, b0, acc[0], 0, 0, 0);
        acc[1] = __builtin_amdgcn_mfma_f32_16x16x32_bf16(af, b1, acc[1], 0, 0, 0);
    }

    #pragma unroll
    for (int n = 0; n < 2; ++n) {
        int col = n * 16 + lr;
        float bv = bb[col];
        #pragma unroll
        for (int r = 0; r < 4; ++r) {
            int row = wave * 16 + (lane >> 4) * 4 + r;
            sem_s[row][col] = acc[n][r] + bv;
        }
    }
    __syncthreads();
    if (tid < 64) {
        int bl = tm * 64 + tid;
        int b = bl >> 7, l = bl & 127;
        float vals[30];
        float sq[3] = {0.f, 0.f, 0.f};
        #pragma unroll
        for (int j = 0; j < 30; ++j) { float v = sem_s[tid][j]; vals[j] = v; sq[j % 3] += v * v; }
        float scl[3];
        #pragma unroll
        for (int c = 0; c < 3; ++c) scl[c] = (sq[c] / (1.f + sq[c])) / sqrtf(sq[c]);
        float* op = sem + (size_t)b * NTASKS * 384 + l * 3;
        #pragma unroll
        for (int j = 0; j < 30; ++j) op[(j / 3) * 384 + (j % 3)] = vals[j] * scl[j % 3];
    }
}

// ---------------- priors[c][b][n][l] = sem[b][n][:] . rw[c][n][:][l] ----------------
#define BBI 16
__global__ void k_priors(const float* __restrict__ sem, const float* __restrict__ rw,
                         float* __restrict__ priors) {
    int cn = blockIdx.y;             // c*10+n
    int c = cn / NTASKS, n = cn % NTASKS;
    int b0 = blockIdx.x * BBI;
    int l = threadIdx.x;             // 128
    __shared__ float sems[BBI][384];
    for (int bbi = 0; bbi < BBI; ++bbi) {
        const float* srow = sem + ((size_t)(b0 + bbi) * NTASKS + n) * 384;
        for (int d = l; d < 384; d += 128) sems[bbi][d] = srow[d];
    }
    __syncthreads();
    float acc[BBI] = {};
    const float* rwp = rw + (size_t)cn * 384 * 128 + l;
    for (int d = 0; d < 384; ++d) {
        float rv = rwp[(size_t)d * 128];
        #pragma unroll
        for (int bbi = 0; bbi < BBI; ++bbi) acc[bbi] += sems[bbi][d] * rv;
    }
    for (int bbi = 0; bbi < BBI; ++bbi)
        priors[(((size_t)c * BATCH + b0 + bbi) * NTASKS + n) * 128 + l] = acc[bbi];
}

// ---------------- dynamic routing; logits are uniform over l ----------------
__global__ void k_routing(const float* __restrict__ priors, const int* tptr,
                          float* __restrict__ vote) {
    int cb = blockIdx.x;             // c*128+b
    int lane = threadIdx.x;          // 64
    int t = *tptr;
    float p0[NTASKS], p1[NTASKS], ln[NTASKS];
    const float* pb = priors + (size_t)cb * NTASKS * 128;
    #pragma unroll
    for (int n = 0; n < NTASKS; ++n) {
        p0[n] = pb[n * 128 + lane];
        p1[n] = pb[n * 128 + 64 + lane];
        ln[n] = 0.f;
    }
    float v0 = 0.f, v1 = 0.f;
    for (int it = 0; it < 3; ++it) {
        float lm[NTASKS];
        float mx = -3.4e38f;
        #pragma unroll
        for (int n = 0; n < NTASKS; ++n) { lm[n] = (n <= t) ? ln[n] : NEGV; mx = fmaxf(mx, lm[n]); }
        float e[NTASKS], se = 0.f;
        #pragma unroll
        for (int n = 0; n < NTASKS; ++n) { e[n] = expf(lm[n] - mx); se += e[n]; }
        float inv = 1.f / se;
        v0 = 0.f; v1 = 0.f;
        #pragma unroll
        for (int n = 0; n < NTASKS; ++n) { float pr = e[n] * inv; v0 += pr * p0[n]; v1 += pr * p1[n]; }
        if (it == 2) break;
        float sq = v0 * v0 + v1 * v1;
        #pragma unroll
        for (int m = 32; m >= 1; m >>= 1) sq += __shfl_xor(sq, m);
        float scale = (sq / (1.f + sq)) / sqrtf(sq);
        float o0 = v0 * scale, o1 = v1 * scale;
        #pragma unroll
        for (int n = 0; n < NTASKS; ++n) {
            float d = p0[n] * o0 + p1[n] * o1;
            #pragma unroll
            for (int m = 32; m >= 1; m >>= 1) d += __shfl_xor(d, m);
            ln[n] = lm[n] + d;
        }
    }
    vote[(size_t)cb * 128 + lane]      = v0;
    vote[(size_t)cb * 128 + 64 + lane] = v1;
}

// ---------------- h = x + (scrambled_vote @ larger_w^T + larger_b) * glarger  -> bf16 ----------------
__global__ void k_buildH(const float* __restrict__ x, const float* __restrict__ vote,
                         const float* __restrict__ lw, const float* __restrict__ lb,
                         const float* __restrict__ glarger, bf16* __restrict__ H) {
    int idx = blockIdx.x * 256 + threadIdx.x;   // over BL*192 float4 groups
    int bl = idx / 192, h4 = (idx % 192) * 4;
    float v0 = vote[bl * 3 + 0], v1 = vote[bl * 3 + 1], v2 = vote[bl * 3 + 2];
    float xa[4];
    *(float4*)xa = ((const float4*)x)[idx];
    bf16x4 o;
    #pragma unroll
    for (int r = 0; r < 4; ++r) {
        int hid = h4 + r;
        float hv = v0 * lw[hid * 3] + v1 * lw[hid * 3 + 1] + v2 * lw[hid * 3 + 2] + lb[hid];
        o[r] = (bf16)(xa[r] + hv * glarger[hid]);
    }
    ((bf16x4*)H)[idx] = o;
}

// ================= 256x256 8-phase MFMA GEMM (m201-style) =================
// A: [M][K] bf16 row-major; Bw: [N][K] bf16 row-major.
// 512 threads = 8 waves; wave (qr=w>>2, qc=w&3); per phase all waves compute one
// 128x128 C-quadrant. LDS: A/B x 2buf x 2half x (128x64 bf16, XOR-swizzled slots).
// MODE 1: Out = bf16 [M][N].  MODE 2: Out = f32, Out = X + val, N==HID.

__device__ __forceinline__ void rd_a(const char* base, bf16x8 (&a)[4][2], int qr, int lr, int kq) {
    #pragma unroll
    for (int m = 0; m < 4; ++m)
        #pragma unroll
        for (int ks = 0; ks < 2; ++ks) {
            int row = qr * 64 + m * 16 + lr;
            a[m][ks] = *(const bf16x8*)(base + row * 128 + (((ks * 4 + kq) ^ (lr & 7)) << 4));
        }
}
__device__ __forceinline__ void rd_b(const char* base, bf16x8 (&b)[2][2], int qc, int lr, int kq) {
    #pragma unroll
    for (int n = 0; n < 2; ++n)
        #pragma unroll
        for (int ks = 0; ks < 2; ++ks) {
            int row = qc * 32 + n * 16 + lr;
            b[n][ks] = *(const bf16x8*)(base + row * 128 + (((ks * 4 + kq) ^ (lr & 7)) << 4));
        }
}
__device__ __forceinline__ void mm8(f32x4 (&acc)[8][4], bf16x8 (&a)[4][2], bf16x8 (&b)[2][2],
                                    int mh, int nh) {
    #pragma unroll
    for (int ks = 0; ks < 2; ++ks)
        #pragma unroll
        for (int m = 0; m < 4; ++m)
            #pragma unroll
            for (int n = 0; n < 2; ++n)
                acc[mh * 4 + m][nh * 2 + n] = __builtin_amdgcn_mfma_f32_16x16x32_bf16(
                    a[m][ks], b[n][ks], acc[mh * 4 + m][nh * 2 + n], 0, 0, 0);
}
__device__ __forceinline__ void phase_mid() {
    __builtin_amdgcn_s_barrier();
    asm volatile("s_waitcnt lgkmcnt(0)" ::: "memory");
    __builtin_amdgcn_sched_barrier(0);
    __builtin_amdgcn_s_setprio(1);
}
__device__ __forceinline__ void phase_end() {
    __builtin_amdgcn_s_setprio(0);
    __builtin_amdgcn_s_barrier();
}

template <int MODE>
__launch_bounds__(512, 2)
__global__ void k_gemm256(const bf16* __restrict__ A, const bf16* __restrict__ Bw,
                          const float* __restrict__ bias, const float* __restrict__ gate,
                          const float* __restrict__ X, void* __restrict__ Out,
                          int K, int N, int TN, int NT) {
    __shared__ __align__(16) char smem[131072];   // A: [0,64K), B: [64K,128K)
    const int tid = threadIdx.x;
    const int lane = tid & 63, w = tid >> 6;
    const int lr = lane & 15, kq = lane >> 4;
    const int qr = w >> 2, qc = w & 3;
    // XCD-aware swizzle (grid % 8 == 0 for both calls)
    int nwg = gridDim.x, bid = blockIdx.x;
    int wg = (bid & 7) * (nwg >> 3) + (bid >> 3);
    int tm = wg / TN, tn = wg % TN;

    // staging geometry: per gld16 issue, wave w covers rows w*8+(lane>>3); lane&7 = 16B slot
    const int r8  = w * 8 + (lane >> 3);
    const int sl8 = ((lane & 7) ^ ((lane >> 3) & 7)) * 8;   // pre-swizzled global col (elems)
    auto stage = [&](const bf16* __restrict__ G, int grow0, int k0, char* slot) {
        const bf16* g0 = G + (size_t)(grow0 + r8) * K + k0 + sl8;
        gld16(g0, slot + w * 1024);
        gld16(g0 + (size_t)64 * K, slot + 8192 + w * 1024);
    };
    auto As_ = [&](int buf, int half) { return smem + ((buf * 2 + half) << 14); };
    auto Bs_ = [&](int buf, int half) { return smem + 65536 + ((buf * 2 + half) << 14); };

    f32x4 acc[8][4] = {};
    bf16x8 a[4][2], b[2][2];

    // ---- prologue: tile0 fully + tile1 {A0,B1}; leaves exactly 2 HTs in flight ----
    stage(A,  tm * 256,       0,  As_(0, 0));
    stage(Bw, tn * 256,       0,  Bs_(0, 0));
    stage(A,  tm * 256 + 128, 0,  As_(0, 1));
    stage(Bw, tn * 256 + 128, 0,  Bs_(0, 1));
    stage(A,  tm * 256,       64, As_(1, 0));
    stage(Bw, tn * 256 + 128, 64, Bs_(1, 1));
    asm volatile("s_waitcnt vmcnt(4)" ::: "memory");
    __builtin_amdgcn_s_barrier();

    for (int T = 0; T < NT; ++T) {
        const int buf = T & 1;
        const bool s1 = (T + 1 < NT), s2 = (T + 2 < NT);
        // ph0: quad(0,0) — read A-half0 + B-half0; stage A1(T+1)
        rd_a(As_(buf, 0), a, qr, lr, kq);
        rd_b(Bs_(buf, 0), b, qc, lr, kq);
        if (s1) stage(A, tm * 256 + 128, (T + 1) * 64, As_(buf ^ 1, 1));
        phase_mid(); mm8(acc, a, b, 0, 0); phase_end();
        // ph1: quad(0,1) — reuse A; read B-half1; stage B0(T+1)
        rd_b(Bs_(buf, 1), b, qc, lr, kq);
        if (s1) stage(Bw, tn * 256, (T + 1) * 64, Bs_(buf ^ 1, 0));
        phase_mid(); mm8(acc, a, b, 0, 1); phase_end();
        // ph2: quad(1,1) — read A-half1; reuse B; stage A0(T+2)
        rd_a(As_(buf, 1), a, qr, lr, kq);
        if (s2) stage(A, tm * 256, (T + 2) * 64, As_(buf, 0));
        phase_mid(); mm8(acc, a, b, 1, 1); phase_end();
        // ph3: quad(1,0) — reuse A; read B-half0; stage B1(T+2); counted vmcnt
        rd_b(Bs_(buf, 0), b, qc, lr, kq);
        if (s2) stage(Bw, tn * 256 + 128, (T + 2) * 64, Bs_(buf, 1));
        phase_mid(); mm8(acc, a, b, 1, 0);
        __builtin_amdgcn_s_setprio(0);
        if (s2) asm volatile("s_waitcnt vmcnt(4)" ::: "memory");
        else    asm volatile("s_waitcnt vmcnt(0)" ::: "memory");
        __builtin_amdgcn_s_barrier();
    }

    // ---- epilogue ----
    #pragma unroll
    for (int in = 0; in < 4; ++in) {
        int col = tn * 256 + (in >> 1) * 128 + qc * 32 + (in & 1) * 16 + lr;
        float bv = bias[col], gv = gate[col];
        #pragma unroll
        for (int im = 0; im < 8; ++im) {
            int row0 = tm * 256 + (im >> 2) * 128 + qr * 64 + (im & 3) * 16 + kq * 4;
            #pragma unroll
            for (int r = 0; r < 4; ++r) {
                float v = fmaxf(acc[im][in][r] + bv, 0.f) * gv;
                int row = row0 + r;
                if (MODE == 1) {
                    ((bf16*)Out)[(size_t)row * N + col] = (bf16)v;
                } else {
                    size_t o = (size_t)row * HID + col;
                    ((float*)Out)[o] = X[o] + v;
                }
            }
        }
    }
}

extern "C" void kernel_launch(void* const* d_in, const int* in_sizes, int n_in,
                              void* d_out, int out_size, void* d_ws, size_t ws_size,
                              hipStream_t stream) {
    const float* x      = (const float*)d_in[0];
    const int*   t      = (const int*)  d_in[1];
    const float* s      = (const float*)d_in[2];
    const float* fc1_w  = (const float*)d_in[3];
    const float* fc1_b  = (const float*)d_in[4];
    const float* fc2_w  = (const float*)d_in[5];
    const float* fc2_b  = (const float*)d_in[6];
    const float* efc1   = (const float*)d_in[7];
    const float* efc2   = (const float*)d_in[8];
    const float* sfc1_w = (const float*)d_in[9];
    const float* sfc1_b = (const float*)d_in[10];
    const float* sfc2_w = (const float*)d_in[11];
    const float* sfc2_b = (const float*)d_in[12];
    const float* rw     = (const float*)d_in[13];
    const float* lw     = (const float*)d_in[14];
    const float* lb     = (const float*)d_in[15];
    const float* elarger= (const float*)d_in[16];

    char* ws = (char*)d_ws;
    size_t off = 0;
    auto alloc = [&](size_t b) { void* p = ws + off; off = (off + b + 255) & ~(size_t)255; return p; };
    float* gfc1    = (float*)alloc(ADAPT * 4);
    float* gfc2    = (float*)alloc(HID * 4);
    float* glarger = (float*)alloc(HID * 4);
    bf16*  Wb      = (bf16*) alloc(32 * HID * 2);
    float* bb      = (float*)alloc(32 * 4);
    bf16*  B1      = (bf16*) alloc((size_t)ADAPT * HID * 2);
    bf16*  B2      = (bf16*) alloc((size_t)ADAPT * HID * 2);
    float* sem     = (float*)alloc((size_t)BATCH * NTASKS * 384 * 4);
    float* priors  = (float*)alloc((size_t)CAP * BATCH * NTASKS * 128 * 4);
    float* vote    = (float*)alloc((size_t)CAP * BATCH * 128 * 4);
    bf16*  H1      = (bf16*) alloc((size_t)BL * ADAPT * 2);
    bf16*  H       = (bf16*)d_out;  // stage bf16 h in the (larger) output buffer

    k_gates  <<<14, 256, 0, stream>>>(efc1, efc2, elarger, s, t, gfc1, gfc2, glarger);
    k_fusew  <<<32, 256, 0, stream>>>(sfc1_w, sfc1_b, sfc2_w, sfc2_b, Wb, bb);
    k_convert<<<3072, 256, 0, stream>>>(fc1_w, fc2_w, B1, B2);
    k_semg   <<<BL / 64, 256, 0, stream>>>(x, Wb, bb, sem);
    k_priors <<<dim3(BATCH / BBI, 30), 128, 0, stream>>>(sem, rw, priors);
    k_routing<<<CAP * BATCH, 64, 0, stream>>>(priors, t, vote);
    k_buildH <<<BL * 192 / 256, 256, 0, stream>>>(x, vote, lw, lb, glarger, H);
    // GEMM1: [16384x768] @ [2048x768]^T -> H1 (bf16)   grid 64*8=512
    k_gemm256<1><<<512, 512, 0, stream>>>(H,  B1, fc1_b, gfc1, nullptr, H1,   HID,   ADAPT, 8, HID / 64);
    // GEMM2: [16384x2048] @ [768x2048]^T + x -> out    grid 64*3=192
    k_gemm256<2><<<192, 512, 0, stream>>>(H1, B2, fc2_b, gfc2, x,       d_out, ADAPT, HID,  3, ADAPT / 64);
}

// Round 5
// 198.660 us; speedup vs baseline: 1.7756x; 1.3040x over previous
//
#include <hip/hip_runtime.h>
#include <hip/hip_bf16.h>
#include <math.h>
#include <stdint.h>

typedef __bf16 bf16;
typedef __bf16 bf16x8 __attribute__((ext_vector_type(8)));
typedef __bf16 bf16x4 __attribute__((ext_vector_type(4)));
typedef float  f32x4  __attribute__((ext_vector_type(4)));

#define NTASKS 10
#define CAP    3
#define SEQ    128
#define HID    768
#define ADAPT  2048
#define BATCH  128
#define BL     (BATCH*SEQ)   /* 16384 */
#define NEGV   (-10000.0f)

__device__ __forceinline__ float sigmoidf_(float z) { return 1.f / (1.f + expf(-z)); }

// ---- async global->LDS, 16B per lane; LDS dest = wave-uniform base + lane*16 ----
__device__ __forceinline__ void gld16(const void* g, void* l) {
    auto gp = (const __attribute__((address_space(1))) uint32_t*)g;
    auto lp = (__attribute__((address_space(3))) uint32_t*)(uint32_t)(uintptr_t)l;
    __builtin_amdgcn_global_load_lds(gp, lp, 16, 0, 0);
}

// ---------------- gates: sigmoid(s * e*) ----------------
__global__ void k_gates(const float* efc1, const float* efc2, const float* elarger,
                        const float* s, const int* tptr,
                        float* gfc1, float* gfc2, float* glarger) {
    int i = blockIdx.x * 256 + threadIdx.x;
    int t = *tptr; float sv = *s;
    if (i < ADAPT)                gfc1[i] = sigmoidf_(sv * efc1[t * ADAPT + i]);
    else if (i < ADAPT + HID)     { int j = i - ADAPT;        gfc2[j]    = sigmoidf_(sv * efc2[t * HID + j]); }
    else if (i < ADAPT + 2 * HID) { int j = i - ADAPT - HID;  glarger[j] = sigmoidf_(sv * elarger[t * HID + j]); }
}

// ---- fuse semantic fc1+fc2 into bf16 Wb[32][768] (rows 30,31 zero) + f32 bb[32] ----
__global__ void k_fusew(const float* sfc1_w, const float* sfc1_b,
                        const float* sfc2_w, const float* sfc2_b,
                        bf16* Wb, float* bb) {
    int j = blockIdx.x;        // 0..31
    int n = j / CAP;
    if (j >= 30) {
        for (int i = threadIdx.x; i < HID; i += 256) Wb[j * HID + i] = (bf16)0.f;
        if (threadIdx.x == 0) bb[j] = 0.f;
        return;
    }
    __shared__ float w2[100];
    if (threadIdx.x < 100) w2[threadIdx.x] = sfc2_w[j * 100 + threadIdx.x];
    __syncthreads();
    const float* w1 = sfc1_w + (size_t)n * 100 * HID;
    float a0 = 0, a1 = 0, a2 = 0;
    for (int k = 0; k < 100; ++k) {
        float s2 = w2[k];
        const float* r = w1 + k * HID;
        a0 += s2 * r[threadIdx.x];
        a1 += s2 * r[threadIdx.x + 256];
        a2 += s2 * r[threadIdx.x + 512];
    }
    Wb[j * HID + threadIdx.x]       = (bf16)a0;
    Wb[j * HID + threadIdx.x + 256] = (bf16)a1;
    Wb[j * HID + threadIdx.x + 512] = (bf16)a2;
    if (threadIdx.x == 0) {
        float b = sfc2_b[j];
        for (int k = 0; k < 100; ++k) b += sfc1_b[n * 100 + k] * w2[k];
        bb[j] = b;
    }
}

// ---------------- fp32 -> bf16 weight conversion ----------------
__global__ void k_convert(const float* fc1_w, const float* fc2_w, bf16* B1, bf16* B2) {
    int i = blockIdx.x * 256 + threadIdx.x;
    const int quarter = ADAPT * HID / 4;  // 393216 float4's per weight
    if (i < quarter) {
        float4 v = ((const float4*)fc1_w)[i];
        bf16x4 o = { (bf16)v.x, (bf16)v.y, (bf16)v.z, (bf16)v.w };
        ((bf16x4*)B1)[i] = o;
    } else if (i < 2 * quarter) {
        int j = i - quarter;
        float4 v = ((const float4*)fc2_w)[j];
        bf16x4 o = { (bf16)v.x, (bf16)v.y, (bf16)v.z, (bf16)v.w };
        ((bf16x4*)B2)[j] = o;
    }
}

// ---- transpose-convert route_weights: rwb[cn][l][d] = bf16(rw[cn][d][l]) ----
__global__ void k_rwT(const float* __restrict__ rw, bf16* __restrict__ rwb) {
    int cn = blockIdx.x;           // 0..29
    int d0 = blockIdx.y * 64;      // 6 tiles of 64 d
    __shared__ float t[64][129];
    const float* src = rw + (size_t)cn * 384 * 128;
    int tid = threadIdx.x;         // 256
    #pragma unroll
    for (int p = 0; p < 8; ++p) {
        int f4 = tid + p * 256;    // 2048 float4 per tile
        int row = f4 >> 5, c4 = (f4 & 31) * 4;
        float4 v = *(const float4*)(src + (size_t)(d0 + row) * 128 + c4);
        t[row][c4] = v.x; t[row][c4 + 1] = v.y; t[row][c4 + 2] = v.z; t[row][c4 + 3] = v.w;
    }
    __syncthreads();
    bf16* dst = rwb + (size_t)cn * 128 * 384 + d0;
    #pragma unroll
    for (int p = 0; p < 4; ++p) {
        int i8 = tid + p * 256;    // 1024 bf16x8 per tile
        int l = i8 >> 3, d8 = (i8 & 7) * 8;
        bf16x8 o;
        #pragma unroll
        for (int i = 0; i < 8; ++i) o[i] = (bf16)t[d8 + i][l];
        *(bf16x8*)(dst + (size_t)l * 384 + d8) = o;
    }
}

// ---------------- semantic caps via MFMA + fused squash -> bf16 semb[n][b][384] ----------------
__launch_bounds__(256)
__global__ void k_semg(const float* __restrict__ x, const bf16* __restrict__ Wb,
                       const float* __restrict__ bb, bf16* __restrict__ semb) {
    __shared__ __align__(16) bf16 As[64 * 32];
    __shared__ __align__(16) bf16 Bs[32 * 32];
    __shared__ float sem_s[64][33];
    const int tid = threadIdx.x;
    const int wave = tid >> 6, lane = tid & 63;
    const int tm = blockIdx.x;
    const int lr = lane & 15, kg = (lane >> 4) * 8;
    f32x4 acc[2] = {};

    const float* xbase = x + (size_t)(tm * 64 + (tid >> 2)) * HID + (tid & 3) * 8;
    const bf16* wbase = Wb + (size_t)(tid >> 2) * HID + (tid & 3) * 8;  // valid for tid<128
    bf16* BsW = Bs + wave * 512;

    for (int k0 = 0; k0 < HID; k0 += 32) {
        float xv[8];
        *(float4*)&xv[0] = *(const float4*)(xbase + k0);
        *(float4*)&xv[4] = *(const float4*)(xbase + k0 + 4);
        __syncthreads();
        if (tid < 128) gld16(wbase + k0, BsW);
        bf16x8 xb;
        #pragma unroll
        for (int i = 0; i < 8; ++i) xb[i] = (bf16)xv[i];
        *(bf16x8*)&As[tid * 8] = xb;
        __syncthreads();
        bf16x8 af = *(const bf16x8*)&As[(wave * 16 + lr) * 32 + kg];
        bf16x8 b0 = *(const bf16x8*)&Bs[lr * 32 + kg];
        bf16x8 b1 = *(const bf16x8*)&Bs[(16 + lr) * 32 + kg];
        acc[0] = __builtin_amdgcn_mfma_f32_16x16x32_bf16(af, b0, acc[0], 0, 0, 0);
        acc[1] = __builtin_amdgcn_mfma_f32_16x16x32_bf16(af, b1, acc[1], 0, 0, 0);
    }

    #pragma unroll
    for (int n = 0; n < 2; ++n) {
        int col = n * 16 + lr;
        float bv = bb[col];
        #pragma unroll
        for (int r = 0; r < 4; ++r) {
            int row = wave * 16 + (lane >> 4) * 4 + r;
            sem_s[row][col] = acc[n][r] + bv;
        }
    }
    __syncthreads();
    if (tid < 64) {
        int bl = tm * 64 + tid;
        int b = bl >> 7, l = bl & 127;
        float vals[30];
        float sq[3] = {0.f, 0.f, 0.f};
        #pragma unroll
        for (int j = 0; j < 30; ++j) { float v = sem_s[tid][j]; vals[j] = v; sq[j % 3] += v * v; }
        float scl[3];
        #pragma unroll
        for (int c = 0; c < 3; ++c) scl[c] = (sq[c] / (1.f + sq[c])) / sqrtf(sq[c]);
        #pragma unroll
        for (int j = 0; j < 30; ++j)
            semb[((size_t)(j / 3) * BATCH + b) * 384 + l * 3 + (j % 3)] = (bf16)(vals[j] * scl[j % 3]);
    }
}

// ---------------- priors via MFMA: 30 blocks of 128x128x384 ----------------
// priors[((c*128+b)*10+n)*128+l] = sum_d semb[n][b][d] * rwb[cn][l][d]
__launch_bounds__(256)
__global__ void k_priorsG(const bf16* __restrict__ semb, const bf16* __restrict__ rwb,
                          float* __restrict__ priors) {
    __shared__ __align__(16) bf16 As[128 * 32];
    __shared__ __align__(16) bf16 Bs[128 * 32];
    const int cn = blockIdx.x;           // c*10+n
    const int c = cn / NTASKS, n = cn % NTASKS;
    const int tid = threadIdx.x;
    const int wave = tid >> 6, lane = tid & 63;
    const int wr = wave >> 1, wc = wave & 1;
    const int lr = lane & 15, kg = (lane >> 4) * 8;
    const int K = 384;
    f32x4 acc[4][4] = {};

    const bf16* Abase = semb + ((size_t)n * BATCH + (tid >> 2)) * K + (tid & 3) * 8;
    const bf16* Bbase = rwb + ((size_t)cn * 128 + (tid >> 2)) * K + (tid & 3) * 8;
    bf16* AsW = As + wave * 512;
    bf16* BsW = Bs + wave * 512;

    for (int k0 = 0; k0 < K; k0 += 32) {
        __syncthreads();
        gld16(Abase + k0, AsW);
        gld16(Abase + k0 + (size_t)64 * K, AsW + 2048);
        gld16(Bbase + k0, BsW);
        gld16(Bbase + k0 + (size_t)64 * K, BsW + 2048);
        __syncthreads();
        bf16x8 af[4], bfr[4];
        #pragma unroll
        for (int m = 0; m < 4; ++m)
            af[m] = *(const bf16x8*)&As[(wr * 64 + m * 16 + lr) * 32 + kg];
        #pragma unroll
        for (int nn = 0; nn < 4; ++nn)
            bfr[nn] = *(const bf16x8*)&Bs[(wc * 64 + nn * 16 + lr) * 32 + kg];
        #pragma unroll
        for (int m = 0; m < 4; ++m)
            #pragma unroll
            for (int nn = 0; nn < 4; ++nn)
                acc[m][nn] = __builtin_amdgcn_mfma_f32_16x16x32_bf16(af[m], bfr[nn], acc[m][nn], 0, 0, 0);
    }

    #pragma unroll
    for (int nn = 0; nn < 4; ++nn) {
        int col = wc * 64 + nn * 16 + lr;
        #pragma unroll
        for (int m = 0; m < 4; ++m) {
            int row0 = wr * 64 + m * 16 + (lane >> 4) * 4;
            #pragma unroll
            for (int r = 0; r < 4; ++r) {
                int row = row0 + r;
                priors[(((size_t)c * BATCH + row) * NTASKS + n) * 128 + col] = acc[m][nn][r];
            }
        }
    }
}

// ---------------- dynamic routing; logits are uniform over l ----------------
__global__ void k_routing(const float* __restrict__ priors, const int* tptr,
                          float* __restrict__ vote) {
    int cb = blockIdx.x;             // c*128+b
    int lane = threadIdx.x;          // 64
    int t = *tptr;
    float p0[NTASKS], p1[NTASKS], ln[NTASKS];
    const float* pb = priors + (size_t)cb * NTASKS * 128;
    #pragma unroll
    for (int n = 0; n < NTASKS; ++n) {
        p0[n] = pb[n * 128 + lane];
        p1[n] = pb[n * 128 + 64 + lane];
        ln[n] = 0.f;
    }
    float v0 = 0.f, v1 = 0.f;
    for (int it = 0; it < 3; ++it) {
        float lm[NTASKS];
        float mx = -3.4e38f;
        #pragma unroll
        for (int n = 0; n < NTASKS; ++n) { lm[n] = (n <= t) ? ln[n] : NEGV; mx = fmaxf(mx, lm[n]); }
        float e[NTASKS], se = 0.f;
        #pragma unroll
        for (int n = 0; n < NTASKS; ++n) { e[n] = expf(lm[n] - mx); se += e[n]; }
        float inv = 1.f / se;
        v0 = 0.f; v1 = 0.f;
        #pragma unroll
        for (int n = 0; n < NTASKS; ++n) { float pr = e[n] * inv; v0 += pr * p0[n]; v1 += pr * p1[n]; }
        if (it == 2) break;
        float sq = v0 * v0 + v1 * v1;
        #pragma unroll
        for (int m = 32; m >= 1; m >>= 1) sq += __shfl_xor(sq, m);
        float scale = (sq / (1.f + sq)) / sqrtf(sq);
        float o0 = v0 * scale, o1 = v1 * scale;
        #pragma unroll
        for (int n = 0; n < NTASKS; ++n) {
            float d = p0[n] * o0 + p1[n] * o1;
            #pragma unroll
            for (int m = 32; m >= 1; m >>= 1) d += __shfl_xor(d, m);
            ln[n] = lm[n] + d;
        }
    }
    vote[(size_t)cb * 128 + lane]      = v0;
    vote[(size_t)cb * 128 + 64 + lane] = v1;
}

// ---------------- h = x + (scrambled_vote @ larger_w^T + larger_b) * glarger  -> bf16 ----------------
__global__ void k_buildH(const float* __restrict__ x, const float* __restrict__ vote,
                         const float* __restrict__ lw, const float* __restrict__ lb,
                         const float* __restrict__ glarger, bf16* __restrict__ H) {
    int idx = blockIdx.x * 256 + threadIdx.x;   // over BL*192 float4 groups
    int bl = idx / 192, h4 = (idx % 192) * 4;
    float v0 = vote[bl * 3 + 0], v1 = vote[bl * 3 + 1], v2 = vote[bl * 3 + 2];
    float xa[4];
    *(float4*)xa = ((const float4*)x)[idx];
    bf16x4 o;
    #pragma unroll
    for (int r = 0; r < 4; ++r) {
        int hid = h4 + r;
        float hv = v0 * lw[hid * 3] + v1 * lw[hid * 3 + 1] + v2 * lw[hid * 3 + 2] + lb[hid];
        o[r] = (bf16)(xa[r] + hv * glarger[hid]);
    }
    ((bf16x4*)H)[idx] = o;
}

// ================= 256x256 8-phase MFMA GEMM (m201-style) =================
__device__ __forceinline__ void rd_a(const char* base, bf16x8 (&a)[4][2], int qr, int lr, int kq) {
    #pragma unroll
    for (int m = 0; m < 4; ++m)
        #pragma unroll
        for (int ks = 0; ks < 2; ++ks) {
            int row = qr * 64 + m * 16 + lr;
            a[m][ks] = *(const bf16x8*)(base + row * 128 + (((ks * 4 + kq) ^ (lr & 7)) << 4));
        }
}
__device__ __forceinline__ void rd_b(const char* base, bf16x8 (&b)[2][2], int qc, int lr, int kq) {
    #pragma unroll
    for (int n = 0; n < 2; ++n)
        #pragma unroll
        for (int ks = 0; ks < 2; ++ks) {
            int row = qc * 32 + n * 16 + lr;
            b[n][ks] = *(const bf16x8*)(base + row * 128 + (((ks * 4 + kq) ^ (lr & 7)) << 4));
        }
}
__device__ __forceinline__ void mm8(f32x4 (&acc)[8][4], bf16x8 (&a)[4][2], bf16x8 (&b)[2][2],
                                    int mh, int nh) {
    #pragma unroll
    for (int ks = 0; ks < 2; ++ks)
        #pragma unroll
        for (int m = 0; m < 4; ++m)
            #pragma unroll
            for (int n = 0; n < 2; ++n)
                acc[mh * 4 + m][nh * 2 + n] = __builtin_amdgcn_mfma_f32_16x16x32_bf16(
                    a[m][ks], b[n][ks], acc[mh * 4 + m][nh * 2 + n], 0, 0, 0);
}
__device__ __forceinline__ void phase_mid() {
    __builtin_amdgcn_s_barrier();
    asm volatile("s_waitcnt lgkmcnt(0)" ::: "memory");
    __builtin_amdgcn_sched_barrier(0);
    __builtin_amdgcn_s_setprio(1);
}
__device__ __forceinline__ void phase_end() {
    __builtin_amdgcn_s_setprio(0);
    __builtin_amdgcn_s_barrier();
}

template <int MODE>
__launch_bounds__(512, 2)
__global__ void k_gemm256(const bf16* __restrict__ A, const bf16* __restrict__ Bw,
                          const float* __restrict__ bias, const float* __restrict__ gate,
                          const float* __restrict__ X, void* __restrict__ Out,
                          int K, int N, int TN, int NT) {
    __shared__ __align__(16) char smem[131072];   // A: [0,64K), B: [64K,128K)
    const int tid = threadIdx.x;
    const int lane = tid & 63, w = tid >> 6;
    const int lr = lane & 15, kq = lane >> 4;
    const int qr = w >> 2, qc = w & 3;
    int nwg = gridDim.x, bid = blockIdx.x;
    int wg = (bid & 7) * (nwg >> 3) + (bid >> 3);
    int tm = wg / TN, tn = wg % TN;

    const int r8  = w * 8 + (lane >> 3);
    const int sl8 = ((lane & 7) ^ ((lane >> 3) & 7)) * 8;   // pre-swizzled global col
    auto stage = [&](const bf16* __restrict__ G, int grow0, int k0, char* slot) {
        const bf16* g0 = G + (size_t)(grow0 + r8) * K + k0 + sl8;
        gld16(g0, slot + w * 1024);
        gld16(g0 + (size_t)64 * K, slot + 8192 + w * 1024);
    };
    auto As_ = [&](int buf, int half) { return smem + ((buf * 2 + half) << 14); };
    auto Bs_ = [&](int buf, int half) { return smem + 65536 + ((buf * 2 + half) << 14); };

    f32x4 acc[8][4] = {};
    bf16x8 a[4][2], b[2][2];

    stage(A,  tm * 256,       0,  As_(0, 0));
    stage(Bw, tn * 256,       0,  Bs_(0, 0));
    stage(A,  tm * 256 + 128, 0,  As_(0, 1));
    stage(Bw, tn * 256 + 128, 0,  Bs_(0, 1));
    stage(A,  tm * 256,       64, As_(1, 0));
    stage(Bw, tn * 256 + 128, 64, Bs_(1, 1));
    asm volatile("s_waitcnt vmcnt(4)" ::: "memory");
    __builtin_amdgcn_s_barrier();

    for (int T = 0; T < NT; ++T) {
        const int buf = T & 1;
        const bool s1 = (T + 1 < NT), s2 = (T + 2 < NT);
        rd_a(As_(buf, 0), a, qr, lr, kq);
        rd_b(Bs_(buf, 0), b, qc, lr, kq);
        if (s1) stage(A, tm * 256 + 128, (T + 1) * 64, As_(buf ^ 1, 1));
        phase_mid(); mm8(acc, a, b, 0, 0); phase_end();
        rd_b(Bs_(buf, 1), b, qc, lr, kq);
        if (s1) stage(Bw, tn * 256, (T + 1) * 64, Bs_(buf ^ 1, 0));
        phase_mid(); mm8(acc, a, b, 0, 1); phase_end();
        rd_a(As_(buf, 1), a, qr, lr, kq);
        if (s2) stage(A, tm * 256, (T + 2) * 64, As_(buf, 0));
        phase_mid(); mm8(acc, a, b, 1, 1); phase_end();
        rd_b(Bs_(buf, 0), b, qc, lr, kq);
        if (s2) stage(Bw, tn * 256 + 128, (T + 2) * 64, Bs_(buf, 1));
        phase_mid(); mm8(acc, a, b, 1, 0);
        __builtin_amdgcn_s_setprio(0);
        if (s2) asm volatile("s_waitcnt vmcnt(4)" ::: "memory");
        else    asm volatile("s_waitcnt vmcnt(0)" ::: "memory");
        __builtin_amdgcn_s_barrier();
    }

    #pragma unroll
    for (int in = 0; in < 4; ++in) {
        int col = tn * 256 + (in >> 1) * 128 + qc * 32 + (in & 1) * 16 + lr;
        float bv = bias[col], gv = gate[col];
        #pragma unroll
        for (int im = 0; im < 8; ++im) {
            int row0 = tm * 256 + (im >> 2) * 128 + qr * 64 + (im & 3) * 16 + kq * 4;
            #pragma unroll
            for (int r = 0; r < 4; ++r) {
                float v = fmaxf(acc[im][in][r] + bv, 0.f) * gv;
                int row = row0 + r;
                if (MODE == 1) {
                    ((bf16*)Out)[(size_t)row * N + col] = (bf16)v;
                } else {
                    size_t o = (size_t)row * HID + col;
                    ((float*)Out)[o] = X[o] + v;
                }
            }
        }
    }
}

extern "C" void kernel_launch(void* const* d_in, const int* in_sizes, int n_in,
                              void* d_out, int out_size, void* d_ws, size_t ws_size,
                              hipStream_t stream) {
    const float* x      = (const float*)d_in[0];
    const int*   t      = (const int*)  d_in[1];
    const float* s      = (const float*)d_in[2];
    const float* fc1_w  = (const float*)d_in[3];
    const float* fc1_b  = (const float*)d_in[4];
    const float* fc2_w  = (const float*)d_in[5];
    const float* fc2_b  = (const float*)d_in[6];
    const float* efc1   = (const float*)d_in[7];
    const float* efc2   = (const float*)d_in[8];
    const float* sfc1_w = (const float*)d_in[9];
    const float* sfc1_b = (const float*)d_in[10];
    const float* sfc2_w = (const float*)d_in[11];
    const float* sfc2_b = (const float*)d_in[12];
    const float* rw     = (const float*)d_in[13];
    const float* lw     = (const float*)d_in[14];
    const float* lb     = (const float*)d_in[15];
    const float* elarger= (const float*)d_in[16];

    char* ws = (char*)d_ws;
    size_t off = 0;
    auto alloc = [&](size_t b) { void* p = ws + off; off = (off + b + 255) & ~(size_t)255; return p; };
    float* gfc1    = (float*)alloc(ADAPT * 4);
    float* gfc2    = (float*)alloc(HID * 4);
    float* glarger = (float*)alloc(HID * 4);
    bf16*  Wb      = (bf16*) alloc(32 * HID * 2);
    float* bb      = (float*)alloc(32 * 4);
    bf16*  B1      = (bf16*) alloc((size_t)ADAPT * HID * 2);
    bf16*  B2      = (bf16*) alloc((size_t)ADAPT * HID * 2);
    bf16*  semb    = (bf16*) alloc((size_t)NTASKS * BATCH * 384 * 2);
    bf16*  rwb     = (bf16*) alloc((size_t)30 * 128 * 384 * 2);
    float* priors  = (float*)alloc((size_t)CAP * BATCH * NTASKS * 128 * 4);
    float* vote    = (float*)alloc((size_t)CAP * BATCH * 128 * 4);
    bf16*  H1      = (bf16*) alloc((size_t)BL * ADAPT * 2);
    bf16*  H       = (bf16*)d_out;  // stage bf16 h in the (larger) output buffer

    k_gates  <<<14, 256, 0, stream>>>(efc1, efc2, elarger, s, t, gfc1, gfc2, glarger);
    k_fusew  <<<32, 256, 0, stream>>>(sfc1_w, sfc1_b, sfc2_w, sfc2_b, Wb, bb);
    k_convert<<<3072, 256, 0, stream>>>(fc1_w, fc2_w, B1, B2);
    k_rwT    <<<dim3(30, 6), 256, 0, stream>>>(rw, rwb);
    k_semg   <<<BL / 64, 256, 0, stream>>>(x, Wb, bb, semb);
    k_priorsG<<<30, 256, 0, stream>>>(semb, rwb, priors);
    k_routing<<<CAP * BATCH, 64, 0, stream>>>(priors, t, vote);
    k_buildH <<<BL * 192 / 256, 256, 0, stream>>>(x, vote, lw, lb, glarger, H);
    // GEMM1: [16384x768] @ [2048x768]^T -> H1 (bf16)   grid 64*8=512
    k_gemm256<1><<<512, 512, 0, stream>>>(H,  B1, fc1_b, gfc1, nullptr, H1,   HID,   ADAPT, 8, HID / 64);
    // GEMM2: [16384x2048] @ [768x2048]^T + x -> out    grid 64*3=192
    k_gemm256<2><<<192, 512, 0, stream>>>(H1, B2, fc2_b, gfc2, x,       d_out, ADAPT, HID,  3, ADAPT / 64);
}